// Round 6
// baseline (466.332 us; speedup 1.0000x reference)
//
#include <hip/hip_runtime.h>
#include <hip/hip_bf16.h>

// Problem constants: B=4, C=64, F=256, T=256, CH=32
typedef __hip_bfloat16 bf16;
typedef __attribute__((ext_vector_type(8))) short bf16x8;
typedef __attribute__((ext_vector_type(4))) float f32x4;
typedef __attribute__((ext_vector_type(16))) float f32x16;
typedef __attribute__((ext_vector_type(8))) unsigned short u16x8;
typedef __attribute__((ext_vector_type(4))) unsigned int u32x4;
typedef __attribute__((ext_vector_type(2))) unsigned int u32x2;

struct ConvP {
  const float* W; const float* bi; const float* g; const float* be;
  const float* m; const float* v; const float* a;
};

// 1/sqrt(32) * log2(e): folded into Q-channel BN params (leaky ReLU is
// positively homogeneous so scale commutes); attention then uses raw exp2.
#define QS (0.17677669529663687f * 1.4426950408889634f)

__device__ __forceinline__ unsigned short f2bf(float f) {
  __hip_bfloat16 h = __float2bfloat16(f);
  return __builtin_bit_cast(unsigned short, h);
}
__device__ __forceinline__ unsigned pack2(float a, float b) {
  return (unsigned)f2bf(a) | (((unsigned)f2bf(b)) << 16);
}
__device__ __forceinline__ float fast_exp2(float x) {
#if __has_builtin(__builtin_amdgcn_exp2f)
  return __builtin_amdgcn_exp2f(x);
#else
  return exp2f(x);
#endif
}

// ---------------------------------------------------------------------------
// Kernel A (v6): fused 1x1 conv + BN + LeakyReLU via 16x16x32 MFMA.
// v6 structural change vs v5 (which was barrier-serialized at 2 blocks/CU,
// 9 __syncthreads, 1.65 TB/s): T split into 128-wide chunks -> grid 2048,
// LDS 38 KB -> 4 blocks/CU; output staging is PER-WAVE (no block barrier
// between compute and emit) -> only 3 barriers (around Xb reuse).
// ---------------------------------------------------------------------------
__global__ __launch_bounds__(256, 4) void conv_qkv(
    const float* __restrict__ inp, const float* __restrict__ x,
    ConvP fqk, ConvP fv, ConvP tqk,
    bf16* __restrict__ Qf, bf16* __restrict__ Kf, bf16* __restrict__ Vf,
    bf16* __restrict__ Qt, bf16* __restrict__ Kt)
{
  __shared__ __attribute__((aligned(16))) unsigned short Xb[64 * 132];     // 16.9 KB
  __shared__ __attribute__((aligned(16))) unsigned short Sw[4][2][32 * 40]; // 20 KB
  __shared__ __attribute__((aligned(8)))  float2 Pc[160];

  const int tid = threadIdx.x;
  const int b  = blockIdx.x >> 9;
  const int f  = (blockIdx.x >> 1) & 255;
  const int th = blockIdx.x & 1;                      // which 128-t chunk
  const size_t gsrc = (size_t)b * 64 * 65536 + (size_t)f * 256 + th * 128;
  const size_t tb   = ((size_t)(b * 256 + f) * 256 + th * 128) * 32;

  const int lane = tid & 63;
  const int wid  = tid >> 6;
  const int m16  = lane & 15;
  const int quad = lane >> 4;

  if (tid < 160) {
    const ConvP& P = (tid < 64) ? fqk : (tid < 128) ? tqk : fv;
    const int o = (tid < 64) ? tid : (tid < 128) ? tid - 64 : tid - 128;
    float A = P.g[o] * rsqrtf(P.v[o] + 1e-5f);
    float B2 = (P.bi[o] - P.m[o]) * A + P.be[o];
    if (tid < 128 && ((o & 1) == 0)) { A *= QS; B2 *= QS; }  // Q channels
    Pc[tid] = make_float2(A, B2);
  }

  // stage 64c x 128t fp32 tile -> bf16 LDS [c][t], stride 132
  auto load_X = [&](const float* __restrict__ src) {
    #pragma unroll
    for (int r = 0; r < 8; ++r) {
      const int idx = r * 256 + tid;
      const int c = idx >> 5;
      const int tl = (idx & 31) * 4;
      const float4 v = *(const float4*)(src + gsrc + (size_t)c * 65536 + tl);
      u32x2 pk = {pack2(v.x, v.y), pack2(v.z, v.w)};
      *(u32x2*)&Xb[c * 132 + tl] = pk;
    }
  };

  auto load_A = [&](const float* __restrict__ W, int rowbase, int ks) {
    const float* p = W + (rowbase + m16) * 64 + ks * 32 + quad * 8;
    const float4 lo = *(const float4*)p;
    const float4 hi = *(const float4*)(p + 4);
    bf16x8 r;
    r[0] = (short)f2bf(lo.x); r[1] = (short)f2bf(lo.y);
    r[2] = (short)f2bf(lo.z); r[3] = (short)f2bf(lo.w);
    r[4] = (short)f2bf(hi.x); r[5] = (short)f2bf(hi.y);
    r[6] = (short)f2bf(hi.z); r[7] = (short)f2bf(hi.w);
    return r;
  };

  // B-frag: X[t = (2*wid+i)*16+m16][k = ks*32+quad*8+j]
  auto load_B = [&](int i, int ks) {
    const int t = (2 * wid + i) * 16 + m16;
    const int i0 = ks * 32 + quad * 8;
    bf16x8 r;
    #pragma unroll
    for (int j = 0; j < 8; ++j) r[j] = (short)Xb[(i0 + j) * 132 + t];
    return r;
  };

  // stream this wave's 32-row staging region out (2 KB contiguous)
  auto emitw = [&](const unsigned short* S, bf16* __restrict__ dst) {
    #pragma unroll
    for (int k = 0; k < 2; ++k) {
      const int chunk = k * 64 + lane;            // 16 B units within region
      const int tloc = chunk >> 2, part = chunk & 3;
      u32x4 v = *(const u32x4*)&S[tloc * 40 + part * 8];
      *(u32x4*)(dst + tb + (size_t)wid * 1024 + (size_t)chunk * 8) = v;
    }
  };

  auto leaky = [](float y, float alpha) { return y > 0.f ? y : alpha * y; };

  load_X(inp);
  __syncthreads();                 // Xb + Pc ready

  bf16x8 Bf[2][2];
  #pragma unroll
  for (int i = 0; i < 2; ++i)
    #pragma unroll
    for (int ks = 0; ks < 2; ++ks) Bf[i][ks] = load_B(i, ks);

  // ---- fqk then tqk (share Bf); per-wave staging, no block syncs ----
  #pragma unroll 1
  for (int which = 0; which < 2; ++which) {
    const ConvP& P = which ? tqk : fqk;
    const int pcb = which ? 64 : 0;
    bf16x8 A[4][2];
    #pragma unroll
    for (int ot = 0; ot < 4; ++ot)
      #pragma unroll
      for (int ks = 0; ks < 2; ++ks) A[ot][ks] = load_A(P.W, ot * 16, ks);
    const float alpha = P.a[0];
    unsigned short* SwQ = &Sw[wid][0][0];
    unsigned short* SwK = &Sw[wid][1][0];
    #pragma unroll
    for (int i = 0; i < 2; ++i) {
      const int tloc = i * 16 + m16;
      #pragma unroll
      for (int ot = 0; ot < 4; ++ot) {
        f32x4 acc = {0.f, 0.f, 0.f, 0.f};
        acc = __builtin_amdgcn_mfma_f32_16x16x32_bf16(A[ot][0], Bf[i][0], acc, 0, 0, 0);
        acc = __builtin_amdgcn_mfma_f32_16x16x32_bf16(A[ot][1], Bf[i][1], acc, 0, 0, 0);
        float y[4];
        #pragma unroll
        for (int r = 0; r < 4; ++r) {
          const float2 pp = Pc[pcb + ot * 16 + quad * 4 + r];
          y[r] = leaky(acc[r] * pp.x + pp.y, alpha);
        }
        const int ch0 = ot * 8 + quad * 2;   // Q/K ch for even/odd o
        *(unsigned*)&SwQ[tloc * 40 + ch0] = pack2(y[0], y[2]);
        *(unsigned*)&SwK[tloc * 40 + ch0] = pack2(y[1], y[3]);
      }
    }
    emitw(SwQ, which ? Qt : Qf);
    emitw(SwK, which ? Kt : Kf);
  }

  __syncthreads();                 // all waves done reading Xb
  load_X(x);
  __syncthreads();

  // ---- fv pass ----
  {
    bf16x8 Bv[2][2];
    #pragma unroll
    for (int i = 0; i < 2; ++i)
      #pragma unroll
      for (int ks = 0; ks < 2; ++ks) Bv[i][ks] = load_B(i, ks);
    bf16x8 A[2][2];
    #pragma unroll
    for (int ot = 0; ot < 2; ++ot)
      #pragma unroll
      for (int ks = 0; ks < 2; ++ks) A[ot][ks] = load_A(fv.W, ot * 16, ks);
    const float alpha = fv.a[0];
    unsigned short* SwV = &Sw[wid][0][0];
    #pragma unroll
    for (int i = 0; i < 2; ++i) {
      const int tloc = i * 16 + m16;
      #pragma unroll
      for (int ot = 0; ot < 2; ++ot) {
        f32x4 acc = {0.f, 0.f, 0.f, 0.f};
        acc = __builtin_amdgcn_mfma_f32_16x16x32_bf16(A[ot][0], Bv[i][0], acc, 0, 0, 0);
        acc = __builtin_amdgcn_mfma_f32_16x16x32_bf16(A[ot][1], Bv[i][1], acc, 0, 0, 0);
        float y[4];
        #pragma unroll
        for (int r = 0; r < 4; ++r) {
          const float2 pp = Pc[128 + ot * 16 + quad * 4 + r];
          y[r] = leaky(acc[r] * pp.x + pp.y, alpha);
        }
        const int ch = ot * 16 + quad * 4;
        *(unsigned*)&SwV[tloc * 40 + ch]     = pack2(y[0], y[1]);
        *(unsigned*)&SwV[tloc * 40 + ch + 2] = pack2(y[2], y[3]);
      }
    }
    emitw(SwV, Vf);
  }
}

// ---------------------------------------------------------------------------
// Attention kernel (v6): S^T formulation.
//   S^T = K*Q^T  (operand swap; K/Q frags identical to v5's loads)
//   -> each lane holds one full softmax ROW (64 vals): reductions = 2 shuffles
//   -> P^T B-frags built IN-REGISTER via 4 ds_bpermute per ks-step (the
//      quad-permutation verified element-wise; no Plds round-trip, 33 KB freed)
//   O^T = V^T * P^T; O/Q direct global (Wsc deleted). LDS 72 -> 37 KB.
// ---------------------------------------------------------------------------
template<bool CAUSAL>
__global__ __launch_bounds__(256, 3) void attn_k(
    const bf16* __restrict__ Qg, const bf16* __restrict__ Kg,
    const bf16* __restrict__ Vg, bf16* __restrict__ Og)
{
  __shared__ __attribute__((aligned(16))) unsigned short Kl[256 * 40];   // 20 KB
  __shared__ __attribute__((aligned(16))) unsigned short Vt[32 * 264];   // 16.9 KB

  const int inst = blockIdx.x;
  const int b = inst >> 8;
  const int s = inst & 255;
  constexpr int RS = CAUSAL ? 32 : 8192;
  const int qbase = CAUSAL ? inst * 8192 : (b * 2097152 + s * 32);

  const int tid = threadIdx.x;
  const int lane = tid & 63;
  const int wid = tid >> 6;
  const int m16 = lane & 15;
  const int quad = lane >> 4;
  const int qh = quad >> 1;        // quad high bit
  const int ql = quad & 1;         // quad low bit

  // ---- prefetch all 4 Q B-frags (direct global; latency hidden by staging)
  bf16x8 qfr[4];
  #pragma unroll
  for (int it = 0; it < 4; ++it) {
    const int rt = wid + 4 * it;
    qfr[it] = *(const bf16x8*)(Qg + qbase + (rt * 16 + m16) * RS + quad * 8);
  }

  // ---- stage K (padded stride 40) ----
  #pragma unroll
  for (int k2 = 0; k2 < 4; ++k2) {
    const int chunk = k2 * 256 + tid;
    const int row = chunk >> 2, part = chunk & 3;
    u32x4 val = *(const u32x4*)(Kg + qbase + row * RS + part * 8);
    *(u32x4*)&Kl[row * 40 + part * 8] = val;
  }
  // ---- stage V transposed ----
  if (tid < 128) {
    const unsigned short* v0 = (const unsigned short*)(Vg + qbase) + (2 * tid) * RS;
    const unsigned short* v1 = v0 + RS;
    u16x8 a[4], c[4];
    #pragma unroll
    for (int q = 0; q < 4; ++q) {
      a[q] = *(const u16x8*)(v0 + 8 * q);
      c[q] = *(const u16x8*)(v1 + 8 * q);
    }
    unsigned int* vt32 = (unsigned int*)Vt;
    #pragma unroll
    for (int cc = 0; cc < 32; ++cc) {
      unsigned lo = a[cc >> 3][cc & 7];
      unsigned hi = c[cc >> 3][cc & 7];
      vt32[cc * 132 + tid] = lo | (hi << 16);
    }
  }
  __syncthreads();

  #pragma unroll 1
  for (int it = 0; it < 4; ++it) {
    const int rt = wid + 4 * it;
    const bf16x8 qf = qfr[it];
    const int nct = CAUSAL ? (rt + 1) : 16;

    // S^T tiles: lane (m16,quad) reg r = S[qr=m16][kcol = ct*16 + quad*4 + r]
    f32x4 acc[16];
    #pragma unroll
    for (int ct = 0; ct < 16; ++ct) {
      if (ct < nct) {
        const bf16x8 kf = *(const bf16x8*)&Kl[(ct * 16 + m16) * 40 + quad * 8];
        f32x4 z = {0.f, 0.f, 0.f, 0.f};
        acc[ct] = __builtin_amdgcn_mfma_f32_16x16x32_bf16(kf, qf, z, 0, 0, 0);
      }
    }
    // diagonal mask + in-lane row max, then 2-shuffle cross-quad max
    float mx = -3e38f;
    #pragma unroll
    for (int ct = 0; ct < 16; ++ct) if (ct < nct) {
      #pragma unroll
      for (int r = 0; r < 4; ++r) {
        float v = acc[ct][r];
        if (CAUSAL && (ct == rt) && (quad * 4 + r > m16)) v = -1e30f;
        acc[ct][r] = v;
        mx = fmaxf(mx, v);
      }
    }
    mx = fmaxf(mx, __shfl_xor(mx, 16));
    mx = fmaxf(mx, __shfl_xor(mx, 32));

    float sum = 0.f;
    uint2 pk[16];
    #pragma unroll
    for (int ct = 0; ct < 16; ++ct) if (ct < nct) {
      float p0 = fast_exp2(acc[ct][0] - mx);
      float p1 = fast_exp2(acc[ct][1] - mx);
      float p2 = fast_exp2(acc[ct][2] - mx);
      float p3 = fast_exp2(acc[ct][3] - mx);
      sum += (p0 + p1) + (p2 + p3);
      pk[ct].x = pack2(p0, p1);
      pk[ct].y = pack2(p2, p3);
    }
    if (CAUSAL && ((rt & 1) == 0)) { pk[rt + 1].x = 0u; pk[rt + 1].y = 0u; }
    sum += __shfl_xor(sum, 16);
    sum += __shfl_xor(sum, 32);
    const float inv = 1.0f / sum;

    // O^T = V^T * P^T
    f32x4 o0 = {0.f, 0.f, 0.f, 0.f}, o1 = {0.f, 0.f, 0.f, 0.f};
    const int ksteps = CAUSAL ? ((rt >> 1) + 1) : 8;
    const int srcA = m16 + 16 * (2 * ql + qh);
    const int srcB = m16 + 16 * (2 * ql + (qh ^ 1));
    #pragma unroll
    for (int ks = 0; ks < 8; ++ks) {
      if (ks < ksteps) {
        // contributions: jh=0 shuffle carries tile 2ks+(quad&1); jh=1 the other
        const uint2 cA = pk[2 * ks + ql];
        const uint2 cB = pk[2 * ks + (ql ^ 1)];
        u32x4 pf;
        pf[0] = (unsigned)__shfl((int)cA.x, srcA);
        pf[1] = (unsigned)__shfl((int)cA.y, srcA);
        pf[2] = (unsigned)__shfl((int)cB.x, srcB);
        pf[3] = (unsigned)__shfl((int)cB.y, srcB);
        const bf16x8 pfrag = __builtin_bit_cast(bf16x8, pf);
        #pragma unroll
        for (int c = 0; c < 2; ++c) {
          u32x4 vv = *(const u32x4*)&Vt[(c * 16 + m16) * 264 + ks * 32 + qh * 16 + ql * 8];
          u32x4 vs;
          vs[0] = qh ? vv[2] : vv[0];
          vs[1] = qh ? vv[3] : vv[1];
          vs[2] = qh ? vv[0] : vv[2];
          vs[3] = qh ? vv[1] : vv[3];
          const bf16x8 vfrag = __builtin_bit_cast(bf16x8, vs);
          if (c == 0) o0 = __builtin_amdgcn_mfma_f32_16x16x32_bf16(vfrag, pfrag, o0, 0, 0, 0);
          else        o1 = __builtin_amdgcn_mfma_f32_16x16x32_bf16(vfrag, pfrag, o1, 0, 0, 0);
        }
      }
    }
    // store O: lane holds O[qr=m16][ch = {quad*4..+3, 16+quad*4..+3}]
    const size_t obase = qbase + (size_t)(rt * 16 + m16) * RS;
    u32x2 s0 = {pack2(o0[0] * inv, o0[1] * inv), pack2(o0[2] * inv, o0[3] * inv)};
    u32x2 s1 = {pack2(o1[0] * inv, o1[1] * inv), pack2(o1[2] * inv, o1[3] * inv)};
    *(u32x2*)(Og + obase + quad * 4)      = s0;
    *(u32x2*)(Og + obase + 16 + quad * 4) = s1;
  }
}

// ---------------------------------------------------------------------------
// Kernel D (v5, unchanged): proj conv (32->64) + BN + LeakyReLU + residual,
// via 32x32x16 MFMA, no LDS staging, full-line fp32 stores.
// ---------------------------------------------------------------------------
__global__ __launch_bounds__(256) void proj_k(
    const bf16* __restrict__ tout, const float* __restrict__ x,
    ConvP pj, float* __restrict__ out)
{
  __shared__ float2 Pc[64];
  const int tid = threadIdx.x;
  const int b = blockIdx.x >> 8;
  const int f = blockIdx.x & 255;
  if (tid < 64) {
    const float A = pj.g[tid] * rsqrtf(pj.v[tid] + 1e-5f);
    const float B2 = (pj.bi[tid] - pj.m[tid]) * A + pj.be[tid];
    Pc[tid] = make_float2(A, B2);
  }
  const int lane = tid & 63;
  const int wid = tid >> 6;
  const int n32 = lane & 31;
  const int h = lane >> 5;

  bf16x8 Afr[2][2];
  #pragma unroll
  for (int ot = 0; ot < 2; ++ot)
    #pragma unroll
    for (int ks = 0; ks < 2; ++ks) {
      const float* p = pj.W + (ot * 32 + n32) * 32 + ks * 16 + h * 8;
      const float4 lo = *(const float4*)p;
      const float4 hi = *(const float4*)(p + 4);
      bf16x8 r;
      r[0] = (short)f2bf(lo.x); r[1] = (short)f2bf(lo.y);
      r[2] = (short)f2bf(lo.z); r[3] = (short)f2bf(lo.w);
      r[4] = (short)f2bf(hi.x); r[5] = (short)f2bf(hi.y);
      r[6] = (short)f2bf(hi.z); r[7] = (short)f2bf(hi.w);
      Afr[ot][ks] = r;
    }
  __syncthreads();

  const float alpha = pj.a[0];
  const size_t gbase = (size_t)b * 64 * 65536 + f * 256;
  const size_t tbase = (size_t)(b * 256 + f) * 8192;

  #pragma unroll
  for (int tt = 0; tt < 2; ++tt) {
    const int t = wid * 64 + tt * 32 + n32;
    const bf16x8 B0 = *(const bf16x8*)(tout + tbase + (size_t)t * 32 + 0 * 16 + h * 8);
    const bf16x8 B1 = *(const bf16x8*)(tout + tbase + (size_t)t * 32 + 1 * 16 + h * 8);
    #pragma unroll
    for (int ot = 0; ot < 2; ++ot) {
      f32x16 acc = {};
      acc = __builtin_amdgcn_mfma_f32_32x32x16_bf16(Afr[ot][0], B0, acc, 0, 0, 0);
      acc = __builtin_amdgcn_mfma_f32_32x32x16_bf16(Afr[ot][1], B1, acc, 0, 0, 0);
      #pragma unroll
      for (int reg = 0; reg < 16; ++reg) {
        const int o = ot * 32 + (reg & 3) + 8 * (reg >> 2) + 4 * h;
        const float2 pp = Pc[o];
        float y = acc[reg] * pp.x + pp.y;
        y = y > 0.f ? y : alpha * y;
        const size_t off = gbase + (size_t)o * 65536 + t;
        out[off] = y + x[off];
      }
    }
  }
}

extern "C" void kernel_launch(void* const* d_in, const int* in_sizes, int n_in,
                              void* d_out, int out_size, void* d_ws, size_t ws_size,
                              hipStream_t stream) {
  const float* inp = (const float*)d_in[0];
  const float* x   = (const float*)d_in[1];
  auto cp = [&](int i) {
    return ConvP{ (const float*)d_in[i],     (const float*)d_in[i + 1],
                  (const float*)d_in[i + 2], (const float*)d_in[i + 3],
                  (const float*)d_in[i + 4], (const float*)d_in[i + 5],
                  (const float*)d_in[i + 6] };
  };
  ConvP fqk = cp(2), fv = cp(9), tqk = cp(16), pj = cp(23);

  char* ws = (char*)d_ws;
  const size_t SZ = (size_t)4 * 256 * 256 * 32 * 2;  // 16 MiB per bf16 buffer
  bf16* Qf = (bf16*)(ws + 0 * SZ);   // (B,F,T,CH)
  bf16* Kf = (bf16*)(ws + 1 * SZ);
  bf16* Vf = (bf16*)(ws + 2 * SZ);
  bf16* Qt = (bf16*)(ws + 3 * SZ);
  bf16* Kt = (bf16*)(ws + 4 * SZ);
  bf16* Ft = (bf16*)(ws + 5 * SZ);   // fout (B,F,T,CH)
  bf16* To = (bf16*)(ws + 0 * SZ);   // tout reuses Qf (dead after f-attn)

  conv_qkv<<<2048, 256, 0, stream>>>(inp, x, fqk, fv, tqk, Qf, Kf, Vf, Qt, Kt);
  attn_k<false><<<1024, 256, 0, stream>>>(Qf, Kf, Vf, Ft);   // freq attention
  attn_k<true><<<1024, 256, 0, stream>>>(Qt, Kt, Ft, To);    // causal time attention
  proj_k<<<1024, 256, 0, stream>>>(To, x, pj, (float*)d_out);
}

// Round 7
// 347.649 us; speedup vs baseline: 1.3414x; 1.3414x over previous
//
#include <hip/hip_runtime.h>
#include <hip/hip_bf16.h>

// Problem constants: B=4, C=64, F=256, T=256, CH=32
typedef __hip_bfloat16 bf16;
typedef __attribute__((ext_vector_type(8))) short bf16x8;
typedef __attribute__((ext_vector_type(4))) float f32x4;
typedef __attribute__((ext_vector_type(16))) float f32x16;
typedef __attribute__((ext_vector_type(8))) unsigned short u16x8;
typedef __attribute__((ext_vector_type(4))) unsigned int u32x4;
typedef __attribute__((ext_vector_type(2))) unsigned int u32x2;

struct ConvP {
  const float* W; const float* bi; const float* g; const float* be;
  const float* m; const float* v; const float* a;
};

// 1/sqrt(32) * log2(e): folded into Q-channel BN params (leaky ReLU is
// positively homogeneous so scale commutes); attention then uses raw exp2.
#define QS (0.17677669529663687f * 1.4426950408889634f)

__device__ __forceinline__ unsigned short f2bf(float f) {
  __hip_bfloat16 h = __float2bfloat16(f);
  return __builtin_bit_cast(unsigned short, h);
}
__device__ __forceinline__ unsigned pack2(float a, float b) {
  return (unsigned)f2bf(a) | (((unsigned)f2bf(b)) << 16);
}
__device__ __forceinline__ float fast_exp2(float x) {
#if __has_builtin(__builtin_amdgcn_exp2f)
  return __builtin_amdgcn_exp2f(x);
#else
  return exp2f(x);
#endif
}

// ---------------------------------------------------------------------------
// Kernel A (v6, unchanged): fused 1x1 conv + BN + LeakyReLU via MFMA.
// T split into 128-wide chunks -> grid 2048, per-wave staging, 3 barriers.
// ---------------------------------------------------------------------------
__global__ __launch_bounds__(256, 4) void conv_qkv(
    const float* __restrict__ inp, const float* __restrict__ x,
    ConvP fqk, ConvP fv, ConvP tqk,
    bf16* __restrict__ Qf, bf16* __restrict__ Kf, bf16* __restrict__ Vf,
    bf16* __restrict__ Qt, bf16* __restrict__ Kt)
{
  __shared__ __attribute__((aligned(16))) unsigned short Xb[64 * 132];      // 16.9 KB
  __shared__ __attribute__((aligned(16))) unsigned short Sw[4][2][32 * 40]; // 20 KB
  __shared__ __attribute__((aligned(8)))  float2 Pc[160];

  const int tid = threadIdx.x;
  const int b  = blockIdx.x >> 9;
  const int f  = (blockIdx.x >> 1) & 255;
  const int th = blockIdx.x & 1;
  const size_t gsrc = (size_t)b * 64 * 65536 + (size_t)f * 256 + th * 128;
  const size_t tb   = ((size_t)(b * 256 + f) * 256 + th * 128) * 32;

  const int lane = tid & 63;
  const int wid  = tid >> 6;
  const int m16  = lane & 15;
  const int quad = lane >> 4;

  if (tid < 160) {
    const ConvP& P = (tid < 64) ? fqk : (tid < 128) ? tqk : fv;
    const int o = (tid < 64) ? tid : (tid < 128) ? tid - 64 : tid - 128;
    float A = P.g[o] * rsqrtf(P.v[o] + 1e-5f);
    float B2 = (P.bi[o] - P.m[o]) * A + P.be[o];
    if (tid < 128 && ((o & 1) == 0)) { A *= QS; B2 *= QS; }  // Q channels
    Pc[tid] = make_float2(A, B2);
  }

  auto load_X = [&](const float* __restrict__ src) {
    #pragma unroll
    for (int r = 0; r < 8; ++r) {
      const int idx = r * 256 + tid;
      const int c = idx >> 5;
      const int tl = (idx & 31) * 4;
      const float4 v = *(const float4*)(src + gsrc + (size_t)c * 65536 + tl);
      u32x2 pk = {pack2(v.x, v.y), pack2(v.z, v.w)};
      *(u32x2*)&Xb[c * 132 + tl] = pk;
    }
  };

  auto load_A = [&](const float* __restrict__ W, int rowbase, int ks) {
    const float* p = W + (rowbase + m16) * 64 + ks * 32 + quad * 8;
    const float4 lo = *(const float4*)p;
    const float4 hi = *(const float4*)(p + 4);
    bf16x8 r;
    r[0] = (short)f2bf(lo.x); r[1] = (short)f2bf(lo.y);
    r[2] = (short)f2bf(lo.z); r[3] = (short)f2bf(lo.w);
    r[4] = (short)f2bf(hi.x); r[5] = (short)f2bf(hi.y);
    r[6] = (short)f2bf(hi.z); r[7] = (short)f2bf(hi.w);
    return r;
  };

  auto load_B = [&](int i, int ks) {
    const int t = (2 * wid + i) * 16 + m16;
    const int i0 = ks * 32 + quad * 8;
    bf16x8 r;
    #pragma unroll
    for (int j = 0; j < 8; ++j) r[j] = (short)Xb[(i0 + j) * 132 + t];
    return r;
  };

  auto emitw = [&](const unsigned short* S, bf16* __restrict__ dst) {
    #pragma unroll
    for (int k = 0; k < 2; ++k) {
      const int chunk = k * 64 + lane;
      const int tloc = chunk >> 2, part = chunk & 3;
      u32x4 v = *(const u32x4*)&S[tloc * 40 + part * 8];
      *(u32x4*)(dst + tb + (size_t)wid * 1024 + (size_t)chunk * 8) = v;
    }
  };

  auto leaky = [](float y, float alpha) { return y > 0.f ? y : alpha * y; };

  load_X(inp);
  __syncthreads();

  bf16x8 Bf[2][2];
  #pragma unroll
  for (int i = 0; i < 2; ++i)
    #pragma unroll
    for (int ks = 0; ks < 2; ++ks) Bf[i][ks] = load_B(i, ks);

  #pragma unroll 1
  for (int which = 0; which < 2; ++which) {
    const ConvP& P = which ? tqk : fqk;
    const int pcb = which ? 64 : 0;
    bf16x8 A[4][2];
    #pragma unroll
    for (int ot = 0; ot < 4; ++ot)
      #pragma unroll
      for (int ks = 0; ks < 2; ++ks) A[ot][ks] = load_A(P.W, ot * 16, ks);
    const float alpha = P.a[0];
    unsigned short* SwQ = &Sw[wid][0][0];
    unsigned short* SwK = &Sw[wid][1][0];
    #pragma unroll
    for (int i = 0; i < 2; ++i) {
      const int tloc = i * 16 + m16;
      #pragma unroll
      for (int ot = 0; ot < 4; ++ot) {
        f32x4 acc = {0.f, 0.f, 0.f, 0.f};
        acc = __builtin_amdgcn_mfma_f32_16x16x32_bf16(A[ot][0], Bf[i][0], acc, 0, 0, 0);
        acc = __builtin_amdgcn_mfma_f32_16x16x32_bf16(A[ot][1], Bf[i][1], acc, 0, 0, 0);
        float y[4];
        #pragma unroll
        for (int r = 0; r < 4; ++r) {
          const float2 pp = Pc[pcb + ot * 16 + quad * 4 + r];
          y[r] = leaky(acc[r] * pp.x + pp.y, alpha);
        }
        const int ch0 = ot * 8 + quad * 2;
        *(unsigned*)&SwQ[tloc * 40 + ch0] = pack2(y[0], y[2]);
        *(unsigned*)&SwK[tloc * 40 + ch0] = pack2(y[1], y[3]);
      }
    }
    emitw(SwQ, which ? Qt : Qf);
    emitw(SwK, which ? Kt : Kf);
  }

  __syncthreads();
  load_X(x);
  __syncthreads();

  {
    bf16x8 Bv[2][2];
    #pragma unroll
    for (int i = 0; i < 2; ++i)
      #pragma unroll
      for (int ks = 0; ks < 2; ++ks) Bv[i][ks] = load_B(i, ks);
    bf16x8 A[2][2];
    #pragma unroll
    for (int ot = 0; ot < 2; ++ot)
      #pragma unroll
      for (int ks = 0; ks < 2; ++ks) A[ot][ks] = load_A(fv.W, ot * 16, ks);
    const float alpha = fv.a[0];
    unsigned short* SwV = &Sw[wid][0][0];
    #pragma unroll
    for (int i = 0; i < 2; ++i) {
      const int tloc = i * 16 + m16;
      #pragma unroll
      for (int ot = 0; ot < 2; ++ot) {
        f32x4 acc = {0.f, 0.f, 0.f, 0.f};
        acc = __builtin_amdgcn_mfma_f32_16x16x32_bf16(A[ot][0], Bv[i][0], acc, 0, 0, 0);
        acc = __builtin_amdgcn_mfma_f32_16x16x32_bf16(A[ot][1], Bv[i][1], acc, 0, 0, 0);
        float y[4];
        #pragma unroll
        for (int r = 0; r < 4; ++r) {
          const float2 pp = Pc[128 + ot * 16 + quad * 4 + r];
          y[r] = leaky(acc[r] * pp.x + pp.y, alpha);
        }
        const int ch = ot * 16 + quad * 4;
        *(unsigned*)&SwV[tloc * 40 + ch]     = pack2(y[0], y[1]);
        *(unsigned*)&SwV[tloc * 40 + ch + 2] = pack2(y[2], y[3]);
      }
    }
    emitw(SwV, Vf);
  }
}

// ---------------------------------------------------------------------------
// Attention kernel (v7): v5 S-form compute, restructured memory.
//  - CAUSAL (t-attn): 1 instance/block (rows contiguous, RS=32). Grid 1024.
//    LDS 39 KB -> 4 blocks/CU.
//  - f-attn (!CAUSAL): 2 ADJACENT t-instances/block (waves 0-1 / 2-3); their
//    64 B half-lines pair up in the same CU's L2 -> no HBM amplification
//    (v6: 189 MB fetch / 200 MB write from per-instance 8-16 B granules).
//    Grid 512. LDS 56 KB -> 2 blocks/CU.
//  - K/Q fragments loaded DIRECT from global (16 rows x full 64 B per
//    instruction); K frags hoisted in VGPRs for f-attn (reused 8x).
//  - P round-trip through per-wave LDS in TWO 128-col phases (halves Plds).
//  - O staged per-wave (Osc) -> 16-row x 64 B store instructions.
// ---------------------------------------------------------------------------
template<bool CAUSAL>
__global__ __launch_bounds__(256, CAUSAL ? 4 : 2) void attn_k(
    const bf16* __restrict__ Qg, const bf16* __restrict__ Kg,
    const bf16* __restrict__ Vg, bf16* __restrict__ Og)
{
  constexpr int NI = CAUSAL ? 1 : 2;
  __shared__ __attribute__((aligned(16))) unsigned short Vt[NI][32 * 264];
  __shared__ __attribute__((aligned(16))) unsigned short Plds[4][16 * 136];
  __shared__ __attribute__((aligned(16))) unsigned short Osc[4][16 * 40];

  const int tid = threadIdx.x;
  const int lane = tid & 63;
  const int wid = tid >> 6;
  const int m16 = lane & 15;
  const int quad = lane >> 4;
  constexpr int RS = CAUSAL ? 32 : 8192;

  int base, inst;
  if (CAUSAL) {
    inst = 0;
    base = blockIdx.x * 8192;
  } else {
    const int b = blockIdx.x >> 7;
    const int t0 = (blockIdx.x & 127) * 2;
    inst = wid >> 1;
    base = b * 2097152 + (t0 + inst) * 32;
  }

  // ---- stage V transposed (per instance) ----
  {
    const int sinst = CAUSAL ? 0 : (tid >> 7);
    const int sj    = CAUSAL ? tid : (tid & 127);
    int sbase;
    if (CAUSAL) sbase = base;
    else        sbase = (blockIdx.x >> 7) * 2097152 + ((blockIdx.x & 127) * 2 + sinst) * 32;
    if (!CAUSAL || tid < 128) {
      const unsigned short* v0 = (const unsigned short*)Vg + sbase + (2 * sj) * RS;
      const unsigned short* v1 = v0 + RS;
      u16x8 a[4], c[4];
      #pragma unroll
      for (int q = 0; q < 4; ++q) {
        a[q] = *(const u16x8*)(v0 + 8 * q);
        c[q] = *(const u16x8*)(v1 + 8 * q);
      }
      unsigned int* vt32 = (unsigned int*)&Vt[sinst][0];
      #pragma unroll
      for (int cc = 0; cc < 32; ++cc) {
        unsigned lo = a[cc >> 3][cc & 7];
        unsigned hi = c[cc >> 3][cc & 7];
        vt32[cc * 132 + sj] = lo | (hi << 16);
      }
    }
  }
  __syncthreads();

  // ---- f-attn: hoist all 16 K fragments (reused 8x) ----
  bf16x8 kfr[16];
  if (!CAUSAL) {
    #pragma unroll
    for (int ct = 0; ct < 16; ++ct)
      kfr[ct] = *(const bf16x8*)(Kg + base + (ct * 16 + m16) * RS + quad * 8);
  }

  unsigned short* P  = &Plds[wid][0];
  unsigned short* Os = &Osc[wid][0];
  const unsigned short* Vti = &Vt[inst][0];
  const int r4 = lane >> 2, p4 = lane & 3;
  constexpr int NIT = CAUSAL ? 4 : 8;

  #pragma unroll 1
  for (int it = 0; it < NIT; ++it) {
    const int rt = CAUSAL ? (wid + 4 * it) : ((wid & 1) + 2 * it);
    const bf16x8 qf = *(const bf16x8*)(Qg + base + (rt * 16 + m16) * RS + quad * 8);
    const int nct = CAUSAL ? (rt + 1) : 16;

    f32x4 acc[16];
    #pragma unroll
    for (int ct = 0; ct < 16; ++ct) {
      if (ct < nct) {
        const bf16x8 kf = CAUSAL
            ? *(const bf16x8*)(Kg + base + (ct * 16 + m16) * RS + quad * 8)
            : kfr[ct];
        f32x4 z = {0.f, 0.f, 0.f, 0.f};
        acc[ct] = __builtin_amdgcn_mfma_f32_16x16x32_bf16(qf, kf, z, 0, 0, 0);
      }
    }
    // mask + row max (D layout: col=lane&15, row=quad*4+reg); log2-domain
    float mx[4] = {-3e38f, -3e38f, -3e38f, -3e38f};
    #pragma unroll
    for (int ct = 0; ct < 16; ++ct) if (ct < nct) {
      #pragma unroll
      for (int r = 0; r < 4; ++r) {
        float v = acc[ct][r];
        if (CAUSAL && (ct == nct - 1) && (m16 > quad * 4 + r)) v = -3e38f;
        acc[ct][r] = v;
        mx[r] = fmaxf(mx[r], v);
      }
    }
    #pragma unroll
    for (int r = 0; r < 4; ++r) {
      float m = mx[r];
      #pragma unroll
      for (int d = 1; d < 16; d <<= 1) m = fmaxf(m, __shfl_xor(m, d, 16));
      mx[r] = m;
    }
    float sum[4] = {0.f, 0.f, 0.f, 0.f};
    #pragma unroll
    for (int ct = 0; ct < 16; ++ct) if (ct < nct) {
      #pragma unroll
      for (int r = 0; r < 4; ++r) {
        float p = fast_exp2(acc[ct][r] - mx[r]);
        acc[ct][r] = p;
        sum[r] += p;
      }
    }
    float inv[4];
    #pragma unroll
    for (int r = 0; r < 4; ++r) {
      float ssum = sum[r];
      #pragma unroll
      for (int d = 1; d < 16; d <<= 1) ssum += __shfl_xor(ssum, d, 16);
      inv[r] = 1.0f / ssum;
    }

    const int ksteps = CAUSAL ? ((rt >> 1) + 1) : 8;
    f32x4 o0 = {0.f, 0.f, 0.f, 0.f}, o1 = {0.f, 0.f, 0.f, 0.f};
    // two 128-col phases: write P half, zero-pad if needed, run 4 ks steps
    #pragma unroll
    for (int h = 0; h < 2; ++h) {
      #pragma unroll
      for (int c8 = 0; c8 < 8; ++c8) {
        const int ct = h * 8 + c8;
        if (ct < nct) {
          #pragma unroll
          for (int r = 0; r < 4; ++r)
            P[(quad * 4 + r) * 136 + c8 * 16 + m16] = f2bf(acc[ct][r]);
        }
      }
      if (CAUSAL && ((rt & 1) == 0) && (((rt + 1) >> 3) == h)) {
        #pragma unroll
        for (int u = 0; u < 4; ++u) {
          const int e = lane + 64 * u;
          P[(e >> 4) * 136 + ((rt + 1) & 7) * 16 + (e & 15)] = 0;
        }
      }
      #pragma unroll
      for (int k4 = 0; k4 < 4; ++k4) {
        const int ks = h * 4 + k4;
        if (ks < ksteps) {
          const bf16x8 pf  = *(const bf16x8*)&P[m16 * 136 + k4 * 32 + quad * 8];
          const bf16x8 vf0 = *(const bf16x8*)&Vti[m16 * 264 + ks * 32 + quad * 8];
          const bf16x8 vf1 = *(const bf16x8*)&Vti[(16 + m16) * 264 + ks * 32 + quad * 8];
          o0 = __builtin_amdgcn_mfma_f32_16x16x32_bf16(pf, vf0, o0, 0, 0, 0);
          o1 = __builtin_amdgcn_mfma_f32_16x16x32_bf16(pf, vf1, o1, 0, 0, 0);
        }
      }
    }
    // normalize, stage O per-wave, store 16 rows x 64 B
    #pragma unroll
    for (int r = 0; r < 4; ++r) {
      Os[(quad * 4 + r) * 40 + m16]      = f2bf(o0[r] * inv[r]);
      Os[(quad * 4 + r) * 40 + 16 + m16] = f2bf(o1[r] * inv[r]);
    }
    {
      u32x4 ov = *(const u32x4*)&Os[r4 * 40 + p4 * 8];
      *(u32x4*)(Og + base + (rt * 16 + r4) * RS + p4 * 8) = ov;
    }
  }
}

// ---------------------------------------------------------------------------
// Kernel D (v5, unchanged): proj conv (32->64) + BN + LeakyReLU + residual,
// via 32x32x16 MFMA, no LDS staging, full-line fp32 stores.
// ---------------------------------------------------------------------------
__global__ __launch_bounds__(256) void proj_k(
    const bf16* __restrict__ tout, const float* __restrict__ x,
    ConvP pj, float* __restrict__ out)
{
  __shared__ float2 Pc[64];
  const int tid = threadIdx.x;
  const int b = blockIdx.x >> 8;
  const int f = blockIdx.x & 255;
  if (tid < 64) {
    const float A = pj.g[tid] * rsqrtf(pj.v[tid] + 1e-5f);
    const float B2 = (pj.bi[tid] - pj.m[tid]) * A + pj.be[tid];
    Pc[tid] = make_float2(A, B2);
  }
  const int lane = tid & 63;
  const int wid = tid >> 6;
  const int n32 = lane & 31;
  const int h = lane >> 5;

  bf16x8 Afr[2][2];
  #pragma unroll
  for (int ot = 0; ot < 2; ++ot)
    #pragma unroll
    for (int ks = 0; ks < 2; ++ks) {
      const float* p = pj.W + (ot * 32 + n32) * 32 + ks * 16 + h * 8;
      const float4 lo = *(const float4*)p;
      const float4 hi = *(const float4*)(p + 4);
      bf16x8 r;
      r[0] = (short)f2bf(lo.x); r[1] = (short)f2bf(lo.y);
      r[2] = (short)f2bf(lo.z); r[3] = (short)f2bf(lo.w);
      r[4] = (short)f2bf(hi.x); r[5] = (short)f2bf(hi.y);
      r[6] = (short)f2bf(hi.z); r[7] = (short)f2bf(hi.w);
      Afr[ot][ks] = r;
    }
  __syncthreads();

  const float alpha = pj.a[0];
  const size_t gbase = (size_t)b * 64 * 65536 + f * 256;
  const size_t tbase = (size_t)(b * 256 + f) * 8192;

  #pragma unroll
  for (int tt = 0; tt < 2; ++tt) {
    const int t = wid * 64 + tt * 32 + n32;
    const bf16x8 B0 = *(const bf16x8*)(tout + tbase + (size_t)t * 32 + 0 * 16 + h * 8);
    const bf16x8 B1 = *(const bf16x8*)(tout + tbase + (size_t)t * 32 + 1 * 16 + h * 8);
    #pragma unroll
    for (int ot = 0; ot < 2; ++ot) {
      f32x16 acc = {};
      acc = __builtin_amdgcn_mfma_f32_32x32x16_bf16(Afr[ot][0], B0, acc, 0, 0, 0);
      acc = __builtin_amdgcn_mfma_f32_32x32x16_bf16(Afr[ot][1], B1, acc, 0, 0, 0);
      #pragma unroll
      for (int reg = 0; reg < 16; ++reg) {
        const int o = ot * 32 + (reg & 3) + 8 * (reg >> 2) + 4 * h;
        const float2 pp = Pc[o];
        float y = acc[reg] * pp.x + pp.y;
        y = y > 0.f ? y : alpha * y;
        const size_t off = gbase + (size_t)o * 65536 + t;
        out[off] = y + x[off];
      }
    }
  }
}

extern "C" void kernel_launch(void* const* d_in, const int* in_sizes, int n_in,
                              void* d_out, int out_size, void* d_ws, size_t ws_size,
                              hipStream_t stream) {
  const float* inp = (const float*)d_in[0];
  const float* x   = (const float*)d_in[1];
  auto cp = [&](int i) {
    return ConvP{ (const float*)d_in[i],     (const float*)d_in[i + 1],
                  (const float*)d_in[i + 2], (const float*)d_in[i + 3],
                  (const float*)d_in[i + 4], (const float*)d_in[i + 5],
                  (const float*)d_in[i + 6] };
  };
  ConvP fqk = cp(2), fv = cp(9), tqk = cp(16), pj = cp(23);

  char* ws = (char*)d_ws;
  const size_t SZ = (size_t)4 * 256 * 256 * 32 * 2;  // 16 MiB per bf16 buffer
  bf16* Qf = (bf16*)(ws + 0 * SZ);   // (B,F,T,CH)
  bf16* Kf = (bf16*)(ws + 1 * SZ);
  bf16* Vf = (bf16*)(ws + 2 * SZ);
  bf16* Qt = (bf16*)(ws + 3 * SZ);
  bf16* Kt = (bf16*)(ws + 4 * SZ);
  bf16* Ft = (bf16*)(ws + 5 * SZ);   // fout (B,F,T,CH)
  bf16* To = (bf16*)(ws + 0 * SZ);   // tout reuses Qf (dead after f-attn)

  conv_qkv<<<2048, 256, 0, stream>>>(inp, x, fqk, fv, tqk, Qf, Kf, Vf, Qt, Kt);
  attn_k<false><<<512, 256, 0, stream>>>(Qf, Kf, Vf, Ft);    // freq attention (paired)
  attn_k<true><<<1024, 256, 0, stream>>>(Qt, Kt, Ft, To);    // causal time attention
  proj_k<<<1024, 256, 0, stream>>>(To, x, pj, (float*)d_out);
}